// Round 8
// baseline (154.198 us; speedup 1.0000x reference)
//
#include <hip/hip_runtime.h>
#include <math.h>

#define NB 2
#define NO 512
#define NQ 512
#define OUT_DIM 128
#define LPAD 516   // logits row pitch (floats); %32==4 -> per-head bank offset 4

typedef __attribute__((ext_vector_type(8))) short short8;   // 8 bf16
typedef __attribute__((ext_vector_type(4))) float f32x4;    // MFMA acc
typedef float v2f __attribute__((ext_vector_type(2)));

__device__ __forceinline__ float softplus_f(float x) {
  return x > 0.0f ? x + log1pf(expf(-x)) : log1pf(expf(x));
}
__device__ __forceinline__ unsigned short bf16_rne(float f) {
  unsigned u = __float_as_uint(f);
  unsigned r = u + 0x7FFFu + ((u >> 16) & 1u);
  return (unsigned short)(r >> 16);
}
__device__ __forceinline__ float bf16_to_f32(unsigned short h) {
  return __uint_as_float(((unsigned)h) << 16);
}

#if defined(__has_builtin)
#if __has_builtin(__builtin_amdgcn_cvt_pk_bf16_f32)
#define HAS_CVT_PK_BF16 1
#endif
#endif

// pack 2 fp32 -> 2 bf16 in one u32 (x = low half)
__device__ __forceinline__ unsigned pack_bf2(float x, float y) {
#ifdef HAS_CVT_PK_BF16
  auto r = __builtin_amdgcn_cvt_pk_bf16_f32(x, y);   // 1 VALU op
  unsigned u; __builtin_memcpy(&u, &r, 4);
  return u;
#else
  unsigned ux = __float_as_uint(x);
  unsigned uy = __float_as_uint(y);
  ux = ux + 0x7FFFu + ((ux >> 16) & 1u);
  uy = uy + 0x7FFFu + ((uy >> 16) & 1u);
  return (ux >> 16) | (uy & 0xFFFF0000u);
#endif
}
// unpack u32 (2 bf16) -> v2f {low, high}
__device__ __forceinline__ v2f unpk_bf2(unsigned u) {
  v2f r; r.x = __uint_as_float(u << 16); r.y = __uint_as_float(u & 0xFFFF0000u);
  return r;
}
__device__ __forceinline__ v2f splat2(float x) { v2f r; r.x = x; r.y = x; return r; }
__device__ __forceinline__ v2f fma2(v2f a, v2f b, v2f c) { return __builtin_elementwise_fma(a, b, c); }
__device__ __forceinline__ v2f max2(v2f a, v2f b) { return __builtin_elementwise_max(a, b); }

// ---------------------------------------------------------------------------
// Prep, 1024 blocks x 512 threads (4 blocks/CU).
// Blocks 0..511: fused 2-layer MLP, 2 rows/block (hidden in LDS) -> V bf16.
// Blocks 512..1023: AO[b][o][j] bf16, 2 o-rows/block.
__global__ __launch_bounds__(512) void prep_kernel(
    const float* __restrict__ h_obs, const float* __restrict__ fw1,
    const float* __restrict__ fb1, const float* __restrict__ fw2,
    const float* __restrict__ fb2, const float* __restrict__ pos_obs,
    const float* __restrict__ kw1, unsigned short* __restrict__ V_bf,
    unsigned short* __restrict__ AO_bf)
{
  if (blockIdx.x < 512) {
    __shared__ float s_red[2][2][256];
    __shared__ float s_hid[2][256];
    const int n  = threadIdx.x & 255;
    const int ks = threadIdx.x >> 8;      // 0..1
    const int r0 = blockIdx.x * 2;
    const int k0 = ks * 128;
    float a0 = 0.f, a1 = 0.f;
    #pragma unroll 8
    for (int kk = 0; kk < 128; ++kk) {
      int k = k0 + kk;
      float w = fw1[k * 256 + n];
      a0 = fmaf(h_obs[(r0 + 0) * 256 + k], w, a0);
      a1 = fmaf(h_obs[(r0 + 1) * 256 + k], w, a1);
    }
    s_red[ks][0][n] = a0; s_red[ks][1][n] = a1;
    __syncthreads();
    if (ks == 0) {
      float bb = fb1[n];
      s_hid[0][n] = fmaxf(s_red[0][0][n] + s_red[1][0][n] + bb, 0.f);
      s_hid[1][n] = fmaxf(s_red[0][1][n] + s_red[1][1][n] + bb, 0.f);
    }
    __syncthreads();
    float c0 = 0.f, c1 = 0.f;
    #pragma unroll 8
    for (int kk = 0; kk < 128; ++kk) {
      int k = k0 + kk;
      float w = fw2[k * 256 + n];
      c0 = fmaf(s_hid[0][k], w, c0);
      c1 = fmaf(s_hid[1][k], w, c1);
    }
    __syncthreads();
    s_red[ks][0][n] = c0; s_red[ks][1][n] = c1;
    __syncthreads();
    if (ks == 0) {
      float bb = fb2[n];
      V_bf[(size_t)(r0 + 0) * 256 + n] = bf16_rne(s_red[0][0][n] + s_red[1][0][n] + bb);
      V_bf[(size_t)(r0 + 1) * 256 + n] = bf16_rne(s_red[0][1][n] + s_red[1][1][n] + bb);
    }
  } else {
    const int i     = blockIdx.x - 512;   // 0..511
    const int b     = i >> 8;
    const int chunk = i & 255;
    const int ol    = threadIdx.x >> 8;
    const int j     = threadIdx.x & 255;
    const int o     = chunk * 2 + ol;
    float c0 = kw1[3 * 256 + j] - kw1[6 * 256 + j];
    float c1 = kw1[4 * 256 + j] - kw1[7 * 256 + j];
    float c2 = kw1[5 * 256 + j] - kw1[8 * 256 + j];
    const float* p = pos_obs + ((size_t)(b * NO + o)) * 3;
    AO_bf[(size_t)(b * NO + o) * 256 + j] =
        bf16_rne(fmaf(p[0], c0, fmaf(p[1], c1, p[2] * c2)));
  }
}

// ---------------------------------------------------------------------------
// Fused attention + out_proj. QT=2 per block, 512 threads (8 waves).
__global__ __launch_bounds__(512, 6) void attn_fused(
    const unsigned short* __restrict__ V_bf,   // (B*NO, 256) bf16
    const unsigned short* __restrict__ AO_bf,  // (B*NO, 256) bf16
    const float* __restrict__ kw1,       // (9, 256)
    const float* __restrict__ kb1,       // (256)
    const float* __restrict__ kw2,       // (256, 8)
    const float* __restrict__ kb2,       // (8)
    const float* __restrict__ log_sigma, // (8)
    const float* __restrict__ pos_obs,   // (B*NO, 3)
    const float* __restrict__ pos_query, // (B*NQ, 3)
    const float* __restrict__ ow, const float* __restrict__ obias,
    const float* __restrict__ vw, const float* __restrict__ vbias,
    float* __restrict__ out)
{
  __shared__ float s_logits[2][8 * LPAD];        // 33,024 B
  __shared__ __align__(16) char poolA[16512];    // Bfrags 16,384 | s_redC 16,512 | s_pred 8,192
  __shared__ __align__(16) char poolB[4096];     // aq 2K | s_hv 4K
  __shared__ float s_sum[2][8];
  __shared__ float s_invs2[8];
  __shared__ float s_kb2v[8];

  short8* Bhi    = (short8*)poolA;               // [kstep*64 + lane]
  short8* Blo    = (short8*)(poolA + 8192);
  float*  s_redC = (float*)poolA;                // [8][LPAD] column-major partials
  float*  s_pred = (float*)poolA;                // [ks][mode][q][128]
  float*  s_aq   = (float*)poolB;                // [q*256 + j]
  float*  s_hv   = (float*)poolB;                // [(q*2+mode)*256 + hd]

  const int t   = threadIdx.x;
  const int bq0 = blockIdx.x * 2;
  const int b   = bq0 >> 9;

  // ---- prologue -----------------------------------------------------------
  float pqx[2], pqy[2], pqz[2];
  #pragma unroll
  for (int q = 0; q < 2; ++q) {
    pqx[q] = pos_query[(bq0 + q) * 3 + 0];
    pqy[q] = pos_query[(bq0 + q) * 3 + 1];
    pqz[q] = pos_query[(bq0 + q) * 3 + 2];
  }
  // aq[q][j]
  {
    const int q = t >> 8, j = t & 255;
    float c0 = kw1[0 * 256 + j] + kw1[6 * 256 + j];
    float c1 = kw1[1 * 256 + j] + kw1[7 * 256 + j];
    float c2 = kw1[2 * 256 + j] + kw1[8 * 256 + j];
    s_aq[q * 256 + j] =
        fmaf(pqx[q], c0, fmaf(pqy[q], c1, fmaf(pqz[q], c2, kb1[j])));
  }
  // B fragments: kw2 split bf16 hi/lo
  {
    const int kstep = t >> 6, lane = t & 63;
    const int nh = lane & 15;
    const int kb_ = kstep * 32 + ((lane >> 4) & 3) * 8;
    short8 hi8, lo8;
    #pragma unroll
    for (int i = 0; i < 8; ++i) {
      float v = (nh < 8) ? kw2[(kb_ + i) * 8 + nh] : 0.f;
      unsigned short h = bf16_rne(v);
      hi8[i] = (short)h;
      lo8[i] = (short)bf16_rne(v - bf16_to_f32(h));
    }
    Bhi[kstep * 64 + lane] = hi8;
    Blo[kstep * 64 + lane] = lo8;
  }
  if (t < 8) {
    float s = expf(log_sigma[t]);
    s_invs2[t] = 1.0f / (s * s + 1e-6f);
    s_kb2v[t]  = kb2[t];
  }
  __syncthreads();

  // ---- rbf prefill (uses s_invs2), o = t ----------------------------------
  {
    const int o = t;
    const float* p = pos_obs + (size_t)(b * NO + o) * 3;
    float px = p[0], py = p[1], pz = p[2];
    float d2q[2];
    #pragma unroll
    for (int q = 0; q < 2; ++q) {
      float r0 = pqx[q] - px, r1 = pqy[q] - py, r2 = pqz[q] - pz;
      d2q[q] = r0 * r0 + r1 * r1 + r2 * r2;
    }
    #pragma unroll
    for (int h = 0; h < 8; ++h) {
      float inv = s_invs2[h];
      float kbv = s_kb2v[h];
      s_logits[0][h * LPAD + o] = logf(expf(-d2q[0] * inv) + 1e-8f) + kbv;
      s_logits[1][h * LPAD + o] = logf(expf(-d2q[1] * inv) + 1e-8f) + kbv;
    }
  }

  // ---- phase 1: MFMA delta ------------------------------------------------
  {
    const int wave = t >> 6, lane = t & 63;
    const int quad = lane >> 4, mrow = lane & 15;
    const int tb   = wave * 4;                   // 4 o-tiles per wave, both q
    f32x4 C[2][4];
    #pragma unroll
    for (int q = 0; q < 2; ++q)
      #pragma unroll
      for (int jt = 0; jt < 4; ++jt) C[q][jt] = (f32x4){0.f, 0.f, 0.f, 0.f};

    for (int kstep = 0; kstep < 8; ++kstep) {
      const int koff = kstep * 32 + quad * 8;
      const v2f* aqp0 = (const v2f*)(s_aq + koff);
      const v2f* aqp1 = (const v2f*)(s_aq + 256 + koff);
      v2f aq0[4], aq1[4];
      #pragma unroll
      for (int i = 0; i < 4; ++i) { aq0[i] = aqp0[i]; aq1[i] = aqp1[i]; }
      short8 bhi = Bhi[kstep * 64 + lane];
      short8 blo = Blo[kstep * 64 + lane];
      #pragma unroll
      for (int jt = 0; jt < 4; ++jt) {
        const int o = (tb + jt) * 16 + mrow;
        int4 u = *(const int4*)(AO_bf + ((size_t)(b * NO + o) << 8) + koff);
        v2f ao[4];
        ao[0] = unpk_bf2((unsigned)u.x); ao[1] = unpk_bf2((unsigned)u.y);
        ao[2] = unpk_bf2((unsigned)u.z); ao[3] = unpk_bf2((unsigned)u.w);
        v2f z = splat2(0.f);
        int4 af0, af1;
        {
          v2f h0 = max2(aq0[0] + ao[0], z), h1 = max2(aq0[1] + ao[1], z);
          v2f h2 = max2(aq0[2] + ao[2], z), h3 = max2(aq0[3] + ao[3], z);
          af0.x = (int)pack_bf2(h0.x, h0.y); af0.y = (int)pack_bf2(h1.x, h1.y);
          af0.z = (int)pack_bf2(h2.x, h2.y); af0.w = (int)pack_bf2(h3.x, h3.y);
        }
        {
          v2f h0 = max2(aq1[0] + ao[0], z), h1 = max2(aq1[1] + ao[1], z);
          v2f h2 = max2(aq1[2] + ao[2], z), h3 = max2(aq1[3] + ao[3], z);
          af1.x = (int)pack_bf2(h0.x, h0.y); af1.y = (int)pack_bf2(h1.x, h1.y);
          af1.z = (int)pack_bf2(h2.x, h2.y); af1.w = (int)pack_bf2(h3.x, h3.y);
        }
        short8 a0 = __builtin_bit_cast(short8, af0);
        short8 a1 = __builtin_bit_cast(short8, af1);
        C[0][jt] = __builtin_amdgcn_mfma_f32_16x16x32_bf16(a0, bhi, C[0][jt], 0, 0, 0);
        C[0][jt] = __builtin_amdgcn_mfma_f32_16x16x32_bf16(a0, blo, C[0][jt], 0, 0, 0);
        C[1][jt] = __builtin_amdgcn_mfma_f32_16x16x32_bf16(a1, bhi, C[1][jt], 0, 0, 0);
        C[1][jt] = __builtin_amdgcn_mfma_f32_16x16x32_bf16(a1, blo, C[1][jt], 0, 0, 0);
      }
    }
    __syncthreads();   // prefill writes complete before epilogue +=

    // epilogue: D[n=h=lane&15][m=quad*4+r]; add delta into prefilled logits
    const int h = lane & 15;
    if (h < 8) {
      #pragma unroll
      for (int q = 0; q < 2; ++q)
        #pragma unroll
        for (int jt = 0; jt < 4; ++jt) {
          const int ob = (tb + jt) * 16 + quad * 4;
          #pragma unroll
          for (int r = 0; r < 4; ++r)
            s_logits[q][h * LPAD + ob + r] += C[q][jt][r];
        }
    }
  }
  __syncthreads();

  // ---- phase 2: softmax (8 waves x 2 (q,h) rows) --------------------------
  {
    const int wave = t >> 6, lane = t & 63;
    #pragma unroll
    for (int cc = 0; cc < 2; ++cc) {
      const int c = wave * 2 + cc;
      const int q = c >> 3, h = c & 7;
      float* pl = &s_logits[q][h * LPAD];
      float l[8];
      float m = -1e30f;
      #pragma unroll
      for (int k = 0; k < 8; ++k) {
        l[k] = pl[k * 64 + lane];
        m = fmaxf(m, l[k]);
      }
      #pragma unroll
      for (int off = 32; off >= 1; off >>= 1) m = fmaxf(m, __shfl_xor(m, off, 64));
      float s = 0.f;
      #pragma unroll
      for (int k = 0; k < 8; ++k) {
        float p = expf(l[k] - m);
        pl[k * 64 + lane] = p;
        s += p;
      }
      #pragma unroll
      for (int off = 32; off >= 1; off >>= 1) s += __shfl_xor(s, off, 64);
      if (lane == 0) s_sum[q][h] = s;
    }
  }
  __syncthreads();

  // ---- phase 3: PV + P V^2, V loaded once, both q per thread --------------
  float q1p[8];
  {
    const int s  = t >> 6;                 // o-slice of 64
    const int r  = t & 63;
    const int h  = r >> 3, dg = r & 7;
    const unsigned short* vb_ = V_bf + ((size_t)(b * NO) << 8) + h * 32 + dg * 4;
    const float* P0 = &s_logits[0][h * LPAD + s * 64];
    const float* P1 = &s_logits[1][h * LPAD + s * 64];
    v2f s1a0 = splat2(0.f), s1b0 = splat2(0.f), s2a0 = splat2(0.f), s2b0 = splat2(0.f);
    v2f s1a1 = splat2(0.f), s1b1 = splat2(0.f), s2a1 = splat2(0.f), s2b1 = splat2(0.f);
    const int o0 = s * 64;
    #pragma unroll 2
    for (int oi = 0; oi < 64; oi += 4) {
      float4 pv0 = *(const float4*)&P0[oi];     // ds_read_b128 broadcast
      float4 pv1 = *(const float4*)&P1[oi];
      #pragma unroll
      for (int i = 0; i < 4; ++i) {
        const int o = o0 + oi + i;
        uint2 vv = *(const uint2*)(vb_ + ((size_t)o << 8));
        v2f va  = unpk_bf2(vv.x);
        v2f vb2 = unpk_bf2(vv.y);
        v2f p0 = splat2((&pv0.x)[i]), p1 = splat2((&pv1.x)[i]);
        s1a0 = fma2(p0, va, s1a0);  s1b0 = fma2(p0, vb2, s1b0);
        v2f t0a = p0 * va, t0b = p0 * vb2;
        s2a0 = fma2(t0a, va, s2a0); s2b0 = fma2(t0b, vb2, s2b0);
        s1a1 = fma2(p1, va, s1a1);  s1b1 = fma2(p1, vb2, s1b1);
        v2f t1a = p1 * va, t1b = p1 * vb2;
        s2a1 = fma2(t1a, va, s2a1); s2b1 = fma2(t1b, vb2, s2b1);
      }
    }
    // q0 partials -> column-major LDS (conflict-free b32 writes)
    s_redC[0 * LPAD + t] = s1a0.x; s_redC[1 * LPAD + t] = s1a0.y;
    s_redC[2 * LPAD + t] = s1b0.x; s_redC[3 * LPAD + t] = s1b0.y;
    s_redC[4 * LPAD + t] = s2a0.x; s_redC[5 * LPAD + t] = s2a0.y;
    s_redC[6 * LPAD + t] = s2b0.x; s_redC[7 * LPAD + t] = s2b0.y;
    q1p[0] = s1a1.x; q1p[1] = s1a1.y; q1p[2] = s1b1.x; q1p[3] = s1b1.y;
    q1p[4] = s2a1.x; q1p[5] = s2a1.y; q1p[6] = s2b1.x; q1p[7] = s2b1.y;
  }
  __syncthreads();
  if (t < 256) {                            // reduce q0
    const int hd = t, h = hd >> 5, d = hd & 31, dg = d >> 2, c = d & 3;
    float S1 = 0.f, S2 = 0.f;
    #pragma unroll
    for (int s = 0; s < 8; ++s) {
      const int idx = s * 64 + h * 8 + dg;
      S1 += s_redC[c * LPAD + idx];
      S2 += s_redC[(4 + c) * LPAD + idx];
    }
    float inv = 1.0f / s_sum[0][h];
    float m1 = S1 * inv;
    float va = fmaxf(S2 * inv - m1 * m1, 0.f);
    s_hv[0 * 256 + hd] = m1;
    s_hv[1 * 256 + hd] = va;
  }
  __syncthreads();
  {
    #pragma unroll
    for (int i = 0; i < 8; ++i) s_redC[i * LPAD + t] = q1p[i];
  }
  __syncthreads();
  if (t < 256) {                            // reduce q1
    const int hd = t, h = hd >> 5, d = hd & 31, dg = d >> 2, c = d & 3;
    float S1 = 0.f, S2 = 0.f;
    #pragma unroll
    for (int s = 0; s < 8; ++s) {
      const int idx = s * 64 + h * 8 + dg;
      S1 += s_redC[c * LPAD + idx];
      S2 += s_redC[(4 + c) * LPAD + idx];
    }
    float inv = 1.0f / s_sum[1][h];
    float m1 = S1 * inv;
    float va = fmaxf(S2 * inv - m1 * m1, 0.f);
    s_hv[2 * 256 + hd] = m1;
    s_hv[3 * 256 + hd] = va;
  }
  __syncthreads();

  // ---- phase 4: out_proj, k-split 2, W read once per (mode,ks) ------------
  {
    const int ks = t >> 8, mode = (t >> 7) & 1, n = t & 127;
    const float* W  = mode ? vw : ow;
    const float* X0 = s_hv + mode * 256;        // q0
    const float* X1 = s_hv + (2 + mode) * 256;  // q1
    float a0 = 0.f, a1 = 0.f;
    const int k0 = ks * 128;
    #pragma unroll 4
    for (int k = k0; k < k0 + 128; k += 4) {
      float4 x0 = *(const float4*)&X0[k];
      float4 x1 = *(const float4*)&X1[k];
      float w0 = W[(k + 0) * 128 + n];
      float w1 = W[(k + 1) * 128 + n];
      float w2 = W[(k + 2) * 128 + n];
      float w3 = W[(k + 3) * 128 + n];
      a0 = fmaf(x0.x, w0, a0); a1 = fmaf(x1.x, w0, a1);
      a0 = fmaf(x0.y, w1, a0); a1 = fmaf(x1.y, w1, a1);
      a0 = fmaf(x0.z, w2, a0); a1 = fmaf(x1.z, w2, a1);
      a0 = fmaf(x0.w, w3, a0); a1 = fmaf(x1.w, w3, a1);
    }
    s_pred[((ks * 2 + mode) * 2 + 0) * 128 + n] = a0;
    s_pred[((ks * 2 + mode) * 2 + 1) * 128 + n] = a1;
  }
  __syncthreads();
  {
    const int q = t >> 8, mode = (t >> 7) & 1, n = t & 127;
    float v = s_pred[((0 * 2 + mode) * 2 + q) * 128 + n]
            + s_pred[((1 * 2 + mode) * 2 + q) * 128 + n]
            + (mode ? vbias[n] : obias[n]);
    if (mode) v = softplus_f(v);
    out[(size_t)mode * (NB * NQ * OUT_DIM) + (size_t)(bq0 + q) * OUT_DIM + n] = v;
  }
}

// ---------------------------------------------------------------------------
extern "C" void kernel_launch(void* const* d_in, const int* in_sizes, int n_in,
                              void* d_out, int out_size, void* d_ws, size_t ws_size,
                              hipStream_t stream)
{
  const float* h_obs     = (const float*)d_in[0];
  const float* pos_obs   = (const float*)d_in[1];
  const float* pos_query = (const float*)d_in[2];
  const float* fw1       = (const float*)d_in[3];
  const float* fb1       = (const float*)d_in[4];
  const float* fw2       = (const float*)d_in[5];
  const float* fb2       = (const float*)d_in[6];
  const float* log_sigma = (const float*)d_in[7];
  const float* kw1       = (const float*)d_in[8];
  const float* kb1       = (const float*)d_in[9];
  const float* kw2       = (const float*)d_in[10];
  const float* kb2       = (const float*)d_in[11];
  const float* ow        = (const float*)d_in[12];
  const float* ob        = (const float*)d_in[13];
  const float* vw        = (const float*)d_in[14];
  const float* vb        = (const float*)d_in[15];

  float* out = (float*)d_out;
  unsigned short* ws = (unsigned short*)d_ws;

  unsigned short* V_bf  = ws;            // 262144 ushort = 512 KB
  unsigned short* AO_bf = ws + 262144;   // 262144 ushort

  prep_kernel<<<1024, 512, 0, stream>>>(h_obs, fw1, fb1, fw2, fb2,
                                        pos_obs, kw1, V_bf, AO_bf);
  attn_fused<<<NB * NQ / 2, 512, 0, stream>>>(V_bf, AO_bf, kw1, kb1, kw2, kb2,
                                              log_sigma, pos_obs, pos_query,
                                              ow, ob, vw, vb, out);
}